// Round 7
// baseline (422.244 us; speedup 1.0000x reference)
//
#include <hip/hip_runtime.h>
#include <hip/hip_bf16.h>

typedef __attribute__((ext_vector_type(8))) short bf16x8;  // 8 bf16 (4 VGPRs)
typedef __attribute__((ext_vector_type(4))) short bf16x4;
typedef __attribute__((ext_vector_type(4))) float f32x4;   // MFMA C/D frag

__device__ __forceinline__ short f2bs(float v) {
  __hip_bfloat16 h = __float2bfloat16(v);
  return *reinterpret_cast<short*>(&h);
}

// ================ fused weight transforms + workspace zeroing (one launch) ================
// [0,512) res weights (LDS-coalesced) | [512,616) ds weights (LDS-coalesced)
// [616,872) fc | [872,904) scat w | [904,912) proj w | [912,1424) zero scat | 1424 zero stats
__global__ __launch_bounds__(256) void k_wall(
    const float* __restrict__ rc1w, const float* __restrict__ rc2w,
    const float* __restrict__ d1w, const float* __restrict__ d2w,
    const float* __restrict__ d3w, const float* __restrict__ fcw,
    const float* __restrict__ c1w, const float* __restrict__ pw,
    short* __restrict__ wTr1, short* __restrict__ wTr2, short* __restrict__ wTds1,
    short* __restrict__ wTds2, short* __restrict__ wTds3, short* __restrict__ wfcbf,
    short* __restrict__ wsc, short* __restrict__ wproj,
    float* __restrict__ scatz, float* __restrict__ statsz) {
  __shared__ float ld[128 * 65];
  const int bx = blockIdx.x;
  const int tid = threadIdx.x;
  if (bx < 512) {  // res-conv weights: [l][co][ci][3][3] -> [l][tap][co][ci]
    const float* src = (bx < 256) ? rc1w : rc2w;
    short* dst = (bx < 256) ? wTr1 : wTr2;
    const int cb = bx & 255;
    const float* sp = src + (size_t)cb * 2304;
#pragma unroll
    for (int r = 0; r < 9; ++r) ld[r * 256 + tid] = sp[r * 256 + tid];
    __syncthreads();
    const int g = cb * 256 + tid;  // global (layer,co,ci) index in [0,65536)
    const int layer = g >> 14, win = g & 16383;
    short* dp = dst + (size_t)layer * 147456 + win;
#pragma unroll
    for (int k = 0; k < 9; ++k) dp[k * 16384] = f2bs(ld[tid * 9 + k]);
  } else if (bx < 616) {  // ds weights: [co][ci][16taps] -> [tap][co][ci]
    int base, COCI;
    const float* src;
    short* dst;
    if (bx < 520) { base = 512; COCI = 2048; src = d1w; dst = wTds1; }
    else if (bx < 552) { base = 520; COCI = 8192; src = d2w; dst = wTds2; }
    else { base = 552; COCI = 16384; src = d3w; dst = wTds3; }
    const int cb = bx - base;
    const float* sp = src + (size_t)cb * 4096;
#pragma unroll
    for (int r = 0; r < 16; ++r) {
      const int j = r * 256 + tid;
      ld[j + (j >> 4)] = sp[j];  // pad to stride-17 rows (gcd(17,32)=1)
    }
    __syncthreads();
    const int g = cb * 256 + tid;
    short* dp = dst + g;
#pragma unroll
    for (int k = 0; k < 16; ++k) dp[(size_t)k * COCI] = f2bs(ld[tid * 17 + k]);
  } else if (bx < 872) {  // fc: [j][co*64+pix] -> [j][pix*128+co]
    const int j = bx - 616;
    const float* sp = fcw + (size_t)j * 8192;
    for (int i = tid; i < 8192; i += 256) {
      const int co = i >> 6, pix = i & 63;
      ld[co * 65 + pix] = sp[i];
    }
    __syncthreads();
    short* dp = wfcbf + (size_t)j * 8192;
    for (int i = tid; i < 8192; i += 256) {
      const int pix = i >> 7, co = i & 127;
      dp[i] = f2bs(ld[co * 65 + pix]);
    }
  } else if (bx < 904) {  // scatter weight: [co][ci] f32 -> bf16
    const int i = (bx - 872) * 256 + tid;
    if (i < 8192) wsc[i] = f2bs(c1w[i]);
  } else if (bx < 912) {  // project weight: [co][50] -> [co][64] zero-padded
    const int i = (bx - 904) * 256 + tid;
    if (i < 2048) {
      const int co = i >> 6, k = i & 63;
      wproj[i] = (k < 50) ? f2bs(pw[co * 50 + k]) : (short)0;
    }
  } else if (bx < 1424) {  // zero scat (8M floats over 512 blocks)
    float4* dst = (float4*)(scatz + (size_t)(bx - 912) * 16384);
    const float4 z = {0.f, 0.f, 0.f, 0.f};
    for (int t = tid; t < 4096; t += 256) dst[t] = z;
  } else {  // zero stats + barrier counter + pad
    for (int i = tid; i < 2064; i += 256) statsz[i] = 0.f;
  }
}

// ================ scatter: entity GEMM (MFMA) + relu + scatter-add ================
__global__ __launch_bounds__(256) void k_scatmfma(const float* __restrict__ emb,
                                                  const int* __restrict__ xy,
                                                  const short* __restrict__ wsc,
                                                  float* __restrict__ scat_pm) {
  constexpr int CIP = 264;
  __shared__ short abf[64 * CIP];
  __shared__ int flat[64];
  const int tid = threadIdx.x;
  const int e0 = blockIdx.x * 64;
  const float4* eg = (const float4*)(emb + (size_t)e0 * 256);
  for (int i = tid; i < 4096; i += 256) {
    const int e = i >> 6, k4 = i & 63;
    const float4 v = eg[(size_t)e * 64 + k4];
    bf16x4 o;
    o[0] = f2bs(v.x); o[1] = f2bs(v.y); o[2] = f2bs(v.z); o[3] = f2bs(v.w);
    *(bf16x4*)(&abf[e * CIP + k4 * 4]) = o;
  }
  if (tid < 64) {
    const int* bp = xy + (size_t)(e0 + tid) * 16;
    int xv = 0, yv = 0;
#pragma unroll
    for (int j = 0; j < 8; ++j) xv = (xv << 1) | bp[j];
#pragma unroll
    for (int j = 8; j < 16; ++j) yv = (yv << 1) | bp[j];
    flat[tid] = (bp[0] != -1000000000)
                    ? (((e0 + tid) >> 9) * 4096 + ((yv >> 2) << 6) + (xv >> 2))
                    : -1;
  }
  __syncthreads();
  const int wq = __builtin_amdgcn_readfirstlane(tid >> 6);
  const int lane = tid & 63;
  const int l15 = lane & 15, quad = lane >> 4;
  f32x4 acc[2];
  acc[0] = (f32x4){0.f, 0.f, 0.f, 0.f};
  acc[1] = (f32x4){0.f, 0.f, 0.f, 0.f};
  const short* arow = &abf[(wq * 16 + l15) * CIP + quad * 8];
  const short* w0 = wsc + (size_t)l15 * 256 + quad * 8;
  const short* w1 = wsc + (size_t)(16 + l15) * 256 + quad * 8;
#pragma unroll
  for (int kk = 0; kk < 8; ++kk) {
    bf16x8 a = *(const bf16x8*)(arow + kk * 32);
    acc[0] = __builtin_amdgcn_mfma_f32_16x16x32_bf16(a, *(const bf16x8*)(w0 + kk * 32), acc[0], 0, 0, 0);
    acc[1] = __builtin_amdgcn_mfma_f32_16x16x32_bf16(a, *(const bf16x8*)(w1 + kk * 32), acc[1], 0, 0, 0);
  }
#pragma unroll
  for (int nt = 0; nt < 2; ++nt)
#pragma unroll
    for (int r = 0; r < 4; ++r) {
      const int e = wq * 16 + quad * 4 + r;
      const float v = acc[nt][r];
      const int f = flat[e];
      if (f >= 0 && v > 0.f)
        atomicAdd(&scat_pm[(size_t)f * 32 + nt * 16 + l15], v);
    }
}

// ================ project: concat + 1x1 conv + relu via MFMA -> pm bf16 ================
__global__ __launch_bounds__(256) void k_projmfma(const float* __restrict__ scat_pm,
                                                  const float* __restrict__ xin,
                                                  const short* __restrict__ wproj,
                                                  const float* __restrict__ pb,
                                                  short* __restrict__ h0pm) {
  constexpr int PK = 72;
  __shared__ short abf[128 * PK];
  const int tid = threadIdx.x;
  const int b = blockIdx.x >> 5;
  const int yx0 = (blockIdx.x & 31) << 7;
  const float4* sg = (const float4*)(scat_pm + ((size_t)(b * 4096 + yx0)) * 32);
  for (int i = tid; i < 1024; i += 256) {
    const int p = i >> 3, c4 = i & 7;
    const float4 v = sg[(size_t)p * 8 + c4];
    bf16x4 o;
    o[0] = f2bs(v.x); o[1] = f2bs(v.y); o[2] = f2bs(v.z); o[3] = f2bs(v.w);
    *(bf16x4*)(&abf[p * PK + c4 * 4]) = o;
  }
  for (int i = tid; i < 2304; i += 256) {
    const int run = i >> 7, p = i & 127;
    abf[p * PK + 32 + run] = f2bs(xin[(size_t)(b * 18 + run) * 4096 + yx0 + p]);
  }
  for (int i = tid; i < 2048; i += 256) {
    const int p = i >> 4, k = 50 + (i & 15);
    abf[p * PK + k] = 0;
  }
  __syncthreads();
  const int wq = __builtin_amdgcn_readfirstlane(tid >> 6);
  const int lane = tid & 63;
  const int l15 = lane & 15, quad = lane >> 4;
  f32x4 acc[2][2];
#pragma unroll
  for (int t = 0; t < 2; ++t)
#pragma unroll
    for (int n = 0; n < 2; ++n) acc[t][n] = (f32x4){0.f, 0.f, 0.f, 0.f};
  const short* wb0 = wproj + (size_t)l15 * 64 + quad * 8;
  const short* wb1 = wproj + (size_t)(16 + l15) * 64 + quad * 8;
#pragma unroll
  for (int kk = 0; kk < 2; ++kk) {
    const bf16x8 b0 = *(const bf16x8*)(wb0 + kk * 32);
    const bf16x8 b1 = *(const bf16x8*)(wb1 + kk * 32);
#pragma unroll
    for (int t = 0; t < 2; ++t) {
      const int pix = (wq * 2 + t) * 16 + l15;
      bf16x8 a = *(const bf16x8*)(&abf[pix * PK + quad * 8 + kk * 32]);
      acc[t][0] = __builtin_amdgcn_mfma_f32_16x16x32_bf16(a, b0, acc[t][0], 0, 0, 0);
      acc[t][1] = __builtin_amdgcn_mfma_f32_16x16x32_bf16(a, b1, acc[t][1], 0, 0, 0);
    }
  }
#pragma unroll
  for (int t = 0; t < 2; ++t)
#pragma unroll
    for (int n = 0; n < 2; ++n) {
      const int co = n * 16 + l15;
      const float bv = pb[co];
#pragma unroll
      for (int r = 0; r < 4; ++r) {
        const int pix = (wq * 2 + t) * 16 + quad * 4 + r;
        float v = acc[t][n][r] + bv;
        v = v > 0.f ? v : 0.f;
        h0pm[((size_t)(b * 4096 + yx0 + pix)) * 32 + co] = f2bs(v);
      }
    }
}

// ---------------- 4x4 s2 p1 conv + bias + relu via MFMA, pm bf16 in/out ----------------
// OUTMODE 0: write bf16 out; OUTMODE 2: write f32 out only (ds3 identity)
template <int CIN, int COUT, int HIN, int ROWSO, int COSPLIT, int MT, int NT, int OUTMODE>
__global__ __launch_bounds__(256) void k_ds2(const short* __restrict__ inpm,
                                             const short* __restrict__ wT,
                                             const float* __restrict__ bias,
                                             short* __restrict__ outbf,
                                             float* __restrict__ outf) {
  constexpr int HOUT = HIN / 2;
  constexpr int ROWS = 2 * ROWSO + 2;
  constexpr int COLS = HIN + 2;
  constexpr int CHUNKS = CIN / 8;
  constexpr int KK = CIN / 32;
  constexpr int CIPAD = CIN + 8;
  constexpr int NHO = HOUT / ROWSO;
  __shared__ short lin[ROWS * COLS * CIPAD];
  const int tid = threadIdx.x;
  int bx = blockIdx.x;
  const int co_blk = (COSPLIT > 1) ? (bx % COSPLIT) : 0;
  if (COSPLIT > 1) bx /= COSPLIT;
  const int hoblk = bx % NHO;
  const int b = bx / NHO;
  for (int i = tid; i < ROWS * COLS * CHUNKS; i += 256) {
    const int ch = i % CHUNKS;
    const int pixv = i / CHUNKS;
    const int r = pixv / COLS, c = pixv % COLS;
    const int hi = 2 * ROWSO * hoblk - 1 + r;
    const int wc = c - 1;
    bf16x8 v = (bf16x8)(short)0;
    if (hi >= 0 && hi < HIN && wc >= 0 && wc < HIN)
      v = *(const bf16x8*)(inpm + ((size_t)(b * HIN + hi) * HIN + wc) * CIN + ch * 8);
    *(bf16x8*)(&lin[(r * COLS + c) * CIPAD + ch * 8]) = v;
  }
  __syncthreads();
  const int wq = __builtin_amdgcn_readfirstlane(tid >> 6);
  const int lane = tid & 63;
  const int l15 = lane & 15, quad = lane >> 4;
  const int mtile = (MT > 1) ? (wq % MT) : 0;
  const int cogrp = wq / MT;
  const int cobase = co_blk * (COUT / COSPLIT) + cogrp * (NT * 16);
  const int p = mtile * 16 + l15;
  const int dr = p / HOUT;
  const int col = p % HOUT;
  f32x4 acc[NT];
#pragma unroll
  for (int n = 0; n < NT; ++n) acc[n] = (f32x4){0.f, 0.f, 0.f, 0.f};
  const short* wrow = wT + (size_t)(cobase + l15) * CIN + quad * 8;
  for (int ky = 0; ky < 4; ++ky) {
    for (int kx = 0; kx < 4; ++kx) {
      const short* arow = &lin[((2 * dr + ky) * COLS + 2 * col + kx) * CIPAD + quad * 8];
      const short* wt = wrow + (size_t)(ky * 4 + kx) * COUT * CIN;
#pragma unroll
      for (int kk = 0; kk < KK; ++kk) {
        bf16x8 a = *(const bf16x8*)(arow + kk * 32);
#pragma unroll
        for (int n = 0; n < NT; ++n) {
          bf16x8 bf = *(const bf16x8*)(wt + n * 16 * CIN + kk * 32);
          acc[n] = __builtin_amdgcn_mfma_f32_16x16x32_bf16(a, bf, acc[n], 0, 0, 0);
        }
      }
    }
  }
#pragma unroll
  for (int n = 0; n < NT; ++n) {
    const int co = cobase + n * 16 + l15;
    const float bv = bias[co];
#pragma unroll
    for (int r = 0; r < 4; ++r) {
      const int pp = mtile * 16 + quad * 4 + r;
      const int dr2 = pp / HOUT;
      const int c2 = pp % HOUT;
      const int ho = hoblk * ROWSO + dr2;
      float v = acc[n][r] + bv;
      v = v > 0.f ? v : 0.f;
      const size_t o = ((size_t)b * HOUT * HOUT + ho * HOUT + c2) * COUT + co;
      if constexpr (OUTMODE != 2) outbf[o] = f2bs(v);
      else outf[o] = v;
    }
  }
}

// ================ persistent res tower: 4x(conv+BN+relu) x2 + map_skip + fc-input ================
// 64 blocks (1/image) x 1024 threads (16 waves = 8 co-groups x 2 pixel-halves). All bulk data
// block-local; only BN stats cross blocks via device-scope atomics + bare monotonic counter.
__device__ __forceinline__ void statsync(unsigned* cnt, unsigned target) {
  __syncthreads();  // drains this block's stats atomics (vmcnt(0) before s_barrier)
  if (threadIdx.x == 0) {
    __hip_atomic_fetch_add(cnt, 1u, __ATOMIC_RELAXED, __HIP_MEMORY_SCOPE_AGENT);
    while (__hip_atomic_load(cnt, __ATOMIC_RELAXED, __HIP_MEMORY_SCOPE_AGENT) < target)
      __builtin_amdgcn_s_sleep(1);
  }
  __syncthreads();
}

__global__ __launch_bounds__(1024) void k_res4(
    const float* __restrict__ hf32,  // ds3 f32 output [64][64pix][128]
    const short* __restrict__ wTr1, const short* __restrict__ wTr2,
    const float* __restrict__ rbn1g, const float* __restrict__ rbn1b,
    const float* __restrict__ rbn2g, const float* __restrict__ rbn2b,
    float* __restrict__ stats, unsigned* __restrict__ cnt,
    short* __restrict__ hbf, float* __restrict__ out0) {
  constexpr int CIPAD = 136;
  __shared__ short lin[100 * CIPAD];
  const int tid = threadIdx.x;
  const int b = blockIdx.x;
  const int w = __builtin_amdgcn_readfirstlane(tid >> 6);  // 0..15
  const int cg = w & 7;    // co-group
  const int mg = w >> 3;   // pixel-half: m in {2mg, 2mg+1}
  const int lane = tid & 63;
  const int l15 = lane & 15, quad = lane >> 4;
  const int co = cg * 16 + l15;
  // zero whole tile once (border stays 0; interior overwritten each conv)
  for (int i = tid; i < 1700; i += 1024) *(bf16x8*)(&lin[i * 8]) = (bf16x8)(short)0;
  // identity h and map_skip in registers: j = mi*4+r -> pixel (2mg+mi)*16+quad*4+r, channel co
  float hloc[8], msloc[8];
  {
    const float* hf = hf32 + ((size_t)b << 13);
#pragma unroll
    for (int j = 0; j < 8; ++j) {
      const int pix = (mg * 2 + (j >> 2)) * 16 + quad * 4 + (j & 3);
      const float v = hf[(size_t)pix * 128 + co];
      hloc[j] = v;
      msloc[j] = v;
    }
  }
  unsigned ph = 0;
  for (int i = 0; i < 4; ++i) {
    float* sA = stats + i * 512;
    float* sB = sA + 256;
    __syncthreads();  // guard lin reuse (zero-init on iter 0; prev conv2 reads done)
    // stage h (bf16) into padded 10x10 tile — each (pixel,co) owned by exactly one thread
#pragma unroll
    for (int j = 0; j < 8; ++j) {
      const int pix = (mg * 2 + (j >> 2)) * 16 + quad * 4 + (j & 3);
      const int py = pix >> 3, px = pix & 7;
      lin[((py + 1) * 10 + px + 1) * CIPAD + co] = f2bs(hloc[j]);
    }
    __syncthreads();
    // ---- conv1 ----
    f32x4 acc[2];
    acc[0] = (f32x4){0.f, 0.f, 0.f, 0.f};
    acc[1] = (f32x4){0.f, 0.f, 0.f, 0.f};
    {
      const short* wrow = wTr1 + (size_t)i * 147456 + (size_t)co * 128 + quad * 8;
      for (int t = 0; t < 9; ++t) {
        const int ky = t / 3, kx = t % 3;
        const short* wt = wrow + (size_t)t * 16384;
#pragma unroll
        for (int kk = 0; kk < 4; ++kk) {
          const bf16x8 bfr = *(const bf16x8*)(wt + kk * 32);
#pragma unroll
          for (int mi = 0; mi < 2; ++mi) {
            const int pA = (mg * 2 + mi) * 16 + l15;
            const int py = pA >> 3, px = pA & 7;
            const bf16x8 a =
                *(const bf16x8*)(&lin[((py + ky) * 10 + px + kx) * CIPAD + quad * 8 + kk * 32]);
            acc[mi] = __builtin_amdgcn_mfma_f32_16x16x32_bf16(a, bfr, acc[mi], 0, 0, 0);
          }
        }
      }
    }
    {
      float s = 0.f, q = 0.f;
#pragma unroll
      for (int mi = 0; mi < 2; ++mi)
#pragma unroll
        for (int r = 0; r < 4; ++r) { const float v = acc[mi][r]; s += v; q += v * v; }
      s += __shfl_down(s, 32); q += __shfl_down(q, 32);
      s += __shfl_down(s, 16); q += __shfl_down(q, 16);
      if (lane < 16) {
        atomicAdd(&sA[cg * 16 + lane], s);
        atomicAdd(&sA[128 + cg * 16 + lane], q);
      }
    }
    statsync(cnt, 64u * (++ph));
    // BN1 + relu, staged straight from registers
    {
      const float mu = __hip_atomic_load(&sA[co], __ATOMIC_RELAXED, __HIP_MEMORY_SCOPE_AGENT) * (1.f / 4096.f);
      const float ex2 = __hip_atomic_load(&sA[128 + co], __ATOMIC_RELAXED, __HIP_MEMORY_SCOPE_AGENT) * (1.f / 4096.f);
      const float sc1 = rbn1g[i * 128 + co] * rsqrtf(ex2 - mu * mu + 1e-5f);
      const float sh1 = rbn1b[i * 128 + co] - mu * sc1;
#pragma unroll
      for (int mi = 0; mi < 2; ++mi)
#pragma unroll
        for (int r = 0; r < 4; ++r) {
          const int pix = (mg * 2 + mi) * 16 + quad * 4 + r;
          const int py = pix >> 3, px = pix & 7;
          const float v = acc[mi][r] * sc1 + sh1;
          lin[((py + 1) * 10 + px + 1) * CIPAD + co] = f2bs(v > 0.f ? v : 0.f);
        }
    }
    __syncthreads();
    // ---- conv2 ----
    acc[0] = (f32x4){0.f, 0.f, 0.f, 0.f};
    acc[1] = (f32x4){0.f, 0.f, 0.f, 0.f};
    {
      const short* wrow = wTr2 + (size_t)i * 147456 + (size_t)co * 128 + quad * 8;
      for (int t = 0; t < 9; ++t) {
        const int ky = t / 3, kx = t % 3;
        const short* wt = wrow + (size_t)t * 16384;
#pragma unroll
        for (int kk = 0; kk < 4; ++kk) {
          const bf16x8 bfr = *(const bf16x8*)(wt + kk * 32);
#pragma unroll
          for (int mi = 0; mi < 2; ++mi) {
            const int pA = (mg * 2 + mi) * 16 + l15;
            const int py = pA >> 3, px = pA & 7;
            const bf16x8 a =
                *(const bf16x8*)(&lin[((py + ky) * 10 + px + kx) * CIPAD + quad * 8 + kk * 32]);
            acc[mi] = __builtin_amdgcn_mfma_f32_16x16x32_bf16(a, bfr, acc[mi], 0, 0, 0);
          }
        }
      }
    }
    {
      float s = 0.f, q = 0.f;
#pragma unroll
      for (int mi = 0; mi < 2; ++mi)
#pragma unroll
        for (int r = 0; r < 4; ++r) { const float v = acc[mi][r]; s += v; q += v * v; }
      s += __shfl_down(s, 32); q += __shfl_down(q, 32);
      s += __shfl_down(s, 16); q += __shfl_down(q, 16);
      if (lane < 16) {
        atomicAdd(&sB[cg * 16 + lane], s);
        atomicAdd(&sB[128 + cg * 16 + lane], q);
      }
    }
    statsync(cnt, 64u * (++ph));
    // BN2 + identity + relu + map_skip, all in registers
    {
      const float mu = __hip_atomic_load(&sB[co], __ATOMIC_RELAXED, __HIP_MEMORY_SCOPE_AGENT) * (1.f / 4096.f);
      const float ex2 = __hip_atomic_load(&sB[128 + co], __ATOMIC_RELAXED, __HIP_MEMORY_SCOPE_AGENT) * (1.f / 4096.f);
      const float sc2 = rbn2g[i * 128 + co] * rsqrtf(ex2 - mu * mu + 1e-5f);
      const float sh2 = rbn2b[i * 128 + co] - mu * sc2;
#pragma unroll
      for (int j = 0; j < 8; ++j) {
        float v = acc[j >> 2][j & 3] * sc2 + sh2 + hloc[j];
        v = v > 0.f ? v : 0.f;
        hloc[j] = v;
        msloc[j] += v;
      }
    }
  }
  // epilogue: map_skip canonical [b][co][pix] + fc input bf16 [b][pix*128+co]
  {
    float* ob = out0 + ((size_t)b << 13) + (size_t)co * 64;
    short* hb = hbf + ((size_t)b << 13);
#pragma unroll
    for (int j = 0; j < 8; ++j) {
      const int pix = (mg * 2 + (j >> 2)) * 16 + quad * 4 + (j & 3);
      ob[pix] = msloc[j];
      hb[(size_t)pix * 128 + co] = f2bs(hloc[j]);
    }
  }
}

// ---------------- FC via MFMA: k-split partials ----------------
__global__ __launch_bounds__(256) void k_fcmfma(const short* __restrict__ hbf,
                                                const short* __restrict__ wbf,
                                                float* __restrict__ part) {
  const int nb = blockIdx.x & 3;
  const int kb = blockIdx.x >> 2;
  const int wq = __builtin_amdgcn_readfirstlane((int)(threadIdx.x >> 6));
  const int lane = threadIdx.x & 63;
  const int l15 = lane & 15, quad = lane >> 4;
  const int k0 = kb * 256 + quad * 8;
  const short* wp = wbf + (size_t)(nb * 64 + wq * 16 + l15) * 8192 + k0;
  const short* hp = hbf + (size_t)l15 * 8192 + k0;
  f32x4 acc[4];
#pragma unroll
  for (int m = 0; m < 4; ++m) acc[m] = (f32x4){0.f, 0.f, 0.f, 0.f};
  for (int ks = 0; ks < 8; ++ks) {
    bf16x8 bfr = *(const bf16x8*)(wp + ks * 32);
#pragma unroll
    for (int m = 0; m < 4; ++m) {
      bf16x8 a = *(const bf16x8*)(hp + (size_t)m * 16 * 8192 + ks * 32);
      acc[m] = __builtin_amdgcn_mfma_f32_16x16x32_bf16(a, bfr, acc[m], 0, 0, 0);
    }
  }
#pragma unroll
  for (int m = 0; m < 4; ++m)
#pragma unroll
    for (int r = 0; r < 4; ++r) {
      const int b = m * 16 + quad * 4 + r;
      part[((size_t)kb * 64 + b) * 256 + nb * 64 + wq * 16 + l15] = acc[m][r];
    }
}

__global__ __launch_bounds__(256) void k_fcred(const float* __restrict__ part,
                                               const float* __restrict__ bias,
                                               float* __restrict__ out1) {
  const int idx = blockIdx.x * 256 + threadIdx.x;
  const int j = idx & 255;
  float s = 0.f;
#pragma unroll 8
  for (int kb = 0; kb < 32; ++kb) s += part[(size_t)kb * 16384 + idx];
  const float v = s + bias[j];
  out1[idx] = v > 0.f ? v : 0.f;
}

extern "C" void kernel_launch(void* const* d_in, const int* in_sizes, int n_in,
                              void* d_out, int out_size, void* d_ws, size_t ws_size,
                              hipStream_t stream) {
  const float* xin = (const float*)d_in[0];
  const float* emb = (const float*)d_in[1];
  const int* xy = (const int*)d_in[2];
  const float* c1w = (const float*)d_in[3];
  const float* pw = (const float*)d_in[4];
  const float* pb = (const float*)d_in[5];
  const float* d1w = (const float*)d_in[6];
  const float* d1b = (const float*)d_in[7];
  const float* d2w = (const float*)d_in[8];
  const float* d2b = (const float*)d_in[9];
  const float* d3w = (const float*)d_in[10];
  const float* d3b = (const float*)d_in[11];
  const float* rc1w = (const float*)d_in[12];
  const float* rbn1g = (const float*)d_in[13];
  const float* rbn1b = (const float*)d_in[14];
  const float* rc2w = (const float*)d_in[15];
  const float* rbn2g = (const float*)d_in[16];
  const float* rbn2b = (const float*)d_in[17];
  const float* fcw = (const float*)d_in[18];
  const float* fcb = (const float*)d_in[19];

  float* out0 = (float*)d_out;   // map_skip [64,128,8,8] f32
  float* out1 = out0 + 524288;   // embedded_spatial [64,256] f32

  float* F = (float*)d_ws;
  float* scat = F + 0;                    // [64][4096][32] f32 — dead after projmfma; reused:
  short* h1pm = (short*)(F + 0);          // [64][32][32][64] bf16
  short* h2pm = (short*)(F + 2097152);    // [64][16][16][128] bf16
  float* hf32 = F + 3145728;              // ds3 f32 identity [64][64][128]
  short* hbf = (short*)(F + 5242880);     // final h bf16 (fc input)
  float* stats = F + 6291456;             // 4 layers x 512 + counter + pad (zeroed 2064)
  unsigned* cnt = (unsigned*)(stats + 2048);
  float* fcpart = F + 6293504;            // 32 x [64][256] f32, ends 6817792 < 8388608
  short* h0pm = (short*)(F + 8388608);    // [64][4096][32] bf16
  short* wfcbf = (short*)(F + 12582912);
  short* wTr1 = (short*)(F + 13631488);
  short* wTr2 = wTr1 + 589824;
  short* wTds1 = wTr2 + 589824;
  short* wTds2 = wTds1 + 32768;
  short* wTds3 = wTds2 + 131072;
  short* wsc = wTds3 + 262144;            // 8192 shorts
  short* wproj = wsc + 8192;              // 2048 shorts

  k_wall<<<1425, 256, 0, stream>>>(rc1w, rc2w, d1w, d2w, d3w, fcw, c1w, pw,
                                   wTr1, wTr2, wTds1, wTds2, wTds3, wfcbf, wsc, wproj,
                                   scat, stats);
  k_scatmfma<<<512, 256, 0, stream>>>(emb, xy, wsc, scat);
  k_projmfma<<<2048, 256, 0, stream>>>(scat, xin, wproj, pb, h0pm);
  k_ds2<32, 64, 64, 2, 1, 4, 4, 0><<<1024, 256, 0, stream>>>(h0pm, wTds1, d1b, h1pm, nullptr);
  k_ds2<64, 128, 32, 1, 1, 1, 2, 0><<<1024, 256, 0, stream>>>(h1pm, wTds2, d2b, h2pm, nullptr);
  k_ds2<128, 128, 16, 2, 2, 1, 1, 2><<<512, 256, 0, stream>>>(h2pm, wTds3, d3b, nullptr, hf32);
  k_res4<<<64, 1024, 0, stream>>>(hf32, wTr1, wTr2, rbn1g, rbn1b, rbn2g, rbn2b,
                                  stats, cnt, hbf, out0);
  k_fcmfma<<<128, 256, 0, stream>>>(hbf, wfcbf, fcpart);
  k_fcred<<<64, 256, 0, stream>>>(fcpart, fcb, out1);
}

// Round 8
// 370.210 us; speedup vs baseline: 1.1406x; 1.1406x over previous
//
#include <hip/hip_runtime.h>
#include <hip/hip_bf16.h>

typedef __attribute__((ext_vector_type(8))) short bf16x8;  // 8 bf16 (4 VGPRs)
typedef __attribute__((ext_vector_type(4))) short bf16x4;
typedef __attribute__((ext_vector_type(4))) float f32x4;   // MFMA C/D frag

__device__ __forceinline__ short f2bs(float v) {
  __hip_bfloat16 h = __float2bfloat16(v);
  return *reinterpret_cast<short*>(&h);
}

// ================ fused weight transforms + workspace zeroing (one launch) ================
// [0,512) res weights (LDS-coalesced) | [512,616) ds weights (LDS-coalesced)
// [616,872) fc | [872,904) scat w | [904,912) proj w | [912,1424) zero scat | 1424 zero stats
__global__ __launch_bounds__(256) void k_wall(
    const float* __restrict__ rc1w, const float* __restrict__ rc2w,
    const float* __restrict__ d1w, const float* __restrict__ d2w,
    const float* __restrict__ d3w, const float* __restrict__ fcw,
    const float* __restrict__ c1w, const float* __restrict__ pw,
    short* __restrict__ wTr1, short* __restrict__ wTr2, short* __restrict__ wTds1,
    short* __restrict__ wTds2, short* __restrict__ wTds3, short* __restrict__ wfcbf,
    short* __restrict__ wsc, short* __restrict__ wproj,
    float* __restrict__ scatz, float* __restrict__ statsz) {
  __shared__ float ld[128 * 65];
  const int bx = blockIdx.x;
  const int tid = threadIdx.x;
  if (bx < 512) {  // res-conv weights: [l][co][ci][3][3] -> [l][tap][co][ci]
    const float* src = (bx < 256) ? rc1w : rc2w;
    short* dst = (bx < 256) ? wTr1 : wTr2;
    const int cb = bx & 255;
    const float* sp = src + (size_t)cb * 2304;
#pragma unroll
    for (int r = 0; r < 9; ++r) ld[r * 256 + tid] = sp[r * 256 + tid];
    __syncthreads();
    const int g = cb * 256 + tid;  // global (layer,co,ci) index in [0,65536)
    const int layer = g >> 14, win = g & 16383;
    short* dp = dst + (size_t)layer * 147456 + win;
#pragma unroll
    for (int k = 0; k < 9; ++k) dp[k * 16384] = f2bs(ld[tid * 9 + k]);
  } else if (bx < 616) {  // ds weights: [co][ci][16taps] -> [tap][co][ci]
    int base, COCI;
    const float* src;
    short* dst;
    if (bx < 520) { base = 512; COCI = 2048; src = d1w; dst = wTds1; }
    else if (bx < 552) { base = 520; COCI = 8192; src = d2w; dst = wTds2; }
    else { base = 552; COCI = 16384; src = d3w; dst = wTds3; }
    const int cb = bx - base;
    const float* sp = src + (size_t)cb * 4096;
#pragma unroll
    for (int r = 0; r < 16; ++r) {
      const int j = r * 256 + tid;
      ld[j + (j >> 4)] = sp[j];  // pad to stride-17 rows (gcd(17,32)=1)
    }
    __syncthreads();
    const int g = cb * 256 + tid;
    short* dp = dst + g;
#pragma unroll
    for (int k = 0; k < 16; ++k) dp[(size_t)k * COCI] = f2bs(ld[tid * 17 + k]);
  } else if (bx < 872) {  // fc: [j][co*64+pix] -> [j][pix*128+co]
    const int j = bx - 616;
    const float* sp = fcw + (size_t)j * 8192;
    for (int i = tid; i < 8192; i += 256) {
      const int co = i >> 6, pix = i & 63;
      ld[co * 65 + pix] = sp[i];
    }
    __syncthreads();
    short* dp = wfcbf + (size_t)j * 8192;
    for (int i = tid; i < 8192; i += 256) {
      const int pix = i >> 7, co = i & 127;
      dp[i] = f2bs(ld[co * 65 + pix]);
    }
  } else if (bx < 904) {  // scatter weight: [co][ci] f32 -> bf16
    const int i = (bx - 872) * 256 + tid;
    if (i < 8192) wsc[i] = f2bs(c1w[i]);
  } else if (bx < 912) {  // project weight: [co][50] -> [co][64] zero-padded
    const int i = (bx - 904) * 256 + tid;
    if (i < 2048) {
      const int co = i >> 6, k = i & 63;
      wproj[i] = (k < 50) ? f2bs(pw[co * 50 + k]) : (short)0;
    }
  } else if (bx < 1424) {  // zero scat (8M floats over 512 blocks)
    float4* dst = (float4*)(scatz + (size_t)(bx - 912) * 16384);
    const float4 z = {0.f, 0.f, 0.f, 0.f};
    for (int t = tid; t < 4096; t += 256) dst[t] = z;
  } else {  // zero stats + barrier counter + pad
    for (int i = tid; i < 2064; i += 256) statsz[i] = 0.f;
  }
}

// ================ scatter: entity GEMM (MFMA) + relu + scatter-add ================
__global__ __launch_bounds__(256) void k_scatmfma(const float* __restrict__ emb,
                                                  const int* __restrict__ xy,
                                                  const short* __restrict__ wsc,
                                                  float* __restrict__ scat_pm) {
  constexpr int CIP = 264;
  __shared__ short abf[64 * CIP];
  __shared__ int flat[64];
  const int tid = threadIdx.x;
  const int e0 = blockIdx.x * 64;
  const float4* eg = (const float4*)(emb + (size_t)e0 * 256);
  for (int i = tid; i < 4096; i += 256) {
    const int e = i >> 6, k4 = i & 63;
    const float4 v = eg[(size_t)e * 64 + k4];
    bf16x4 o;
    o[0] = f2bs(v.x); o[1] = f2bs(v.y); o[2] = f2bs(v.z); o[3] = f2bs(v.w);
    *(bf16x4*)(&abf[e * CIP + k4 * 4]) = o;
  }
  if (tid < 64) {
    const int* bp = xy + (size_t)(e0 + tid) * 16;
    int xv = 0, yv = 0;
#pragma unroll
    for (int j = 0; j < 8; ++j) xv = (xv << 1) | bp[j];
#pragma unroll
    for (int j = 8; j < 16; ++j) yv = (yv << 1) | bp[j];
    flat[tid] = (bp[0] != -1000000000)
                    ? (((e0 + tid) >> 9) * 4096 + ((yv >> 2) << 6) + (xv >> 2))
                    : -1;
  }
  __syncthreads();
  const int wq = __builtin_amdgcn_readfirstlane(tid >> 6);
  const int lane = tid & 63;
  const int l15 = lane & 15, quad = lane >> 4;
  f32x4 acc[2];
  acc[0] = (f32x4){0.f, 0.f, 0.f, 0.f};
  acc[1] = (f32x4){0.f, 0.f, 0.f, 0.f};
  const short* arow = &abf[(wq * 16 + l15) * CIP + quad * 8];
  const short* w0 = wsc + (size_t)l15 * 256 + quad * 8;
  const short* w1 = wsc + (size_t)(16 + l15) * 256 + quad * 8;
#pragma unroll
  for (int kk = 0; kk < 8; ++kk) {
    bf16x8 a = *(const bf16x8*)(arow + kk * 32);
    acc[0] = __builtin_amdgcn_mfma_f32_16x16x32_bf16(a, *(const bf16x8*)(w0 + kk * 32), acc[0], 0, 0, 0);
    acc[1] = __builtin_amdgcn_mfma_f32_16x16x32_bf16(a, *(const bf16x8*)(w1 + kk * 32), acc[1], 0, 0, 0);
  }
#pragma unroll
  for (int nt = 0; nt < 2; ++nt)
#pragma unroll
    for (int r = 0; r < 4; ++r) {
      const int e = wq * 16 + quad * 4 + r;
      const float v = acc[nt][r];
      const int f = flat[e];
      if (f >= 0 && v > 0.f)
        atomicAdd(&scat_pm[(size_t)f * 32 + nt * 16 + l15], v);
    }
}

// ================ project: concat + 1x1 conv + relu via MFMA -> pm bf16 ================
__global__ __launch_bounds__(256) void k_projmfma(const float* __restrict__ scat_pm,
                                                  const float* __restrict__ xin,
                                                  const short* __restrict__ wproj,
                                                  const float* __restrict__ pb,
                                                  short* __restrict__ h0pm) {
  constexpr int PK = 72;
  __shared__ short abf[128 * PK];
  const int tid = threadIdx.x;
  const int b = blockIdx.x >> 5;
  const int yx0 = (blockIdx.x & 31) << 7;
  const float4* sg = (const float4*)(scat_pm + ((size_t)(b * 4096 + yx0)) * 32);
  for (int i = tid; i < 1024; i += 256) {
    const int p = i >> 3, c4 = i & 7;
    const float4 v = sg[(size_t)p * 8 + c4];
    bf16x4 o;
    o[0] = f2bs(v.x); o[1] = f2bs(v.y); o[2] = f2bs(v.z); o[3] = f2bs(v.w);
    *(bf16x4*)(&abf[p * PK + c4 * 4]) = o;
  }
  for (int i = tid; i < 2304; i += 256) {
    const int run = i >> 7, p = i & 127;
    abf[p * PK + 32 + run] = f2bs(xin[(size_t)(b * 18 + run) * 4096 + yx0 + p]);
  }
  for (int i = tid; i < 2048; i += 256) {
    const int p = i >> 4, k = 50 + (i & 15);
    abf[p * PK + k] = 0;
  }
  __syncthreads();
  const int wq = __builtin_amdgcn_readfirstlane(tid >> 6);
  const int lane = tid & 63;
  const int l15 = lane & 15, quad = lane >> 4;
  f32x4 acc[2][2];
#pragma unroll
  for (int t = 0; t < 2; ++t)
#pragma unroll
    for (int n = 0; n < 2; ++n) acc[t][n] = (f32x4){0.f, 0.f, 0.f, 0.f};
  const short* wb0 = wproj + (size_t)l15 * 64 + quad * 8;
  const short* wb1 = wproj + (size_t)(16 + l15) * 64 + quad * 8;
#pragma unroll
  for (int kk = 0; kk < 2; ++kk) {
    const bf16x8 b0 = *(const bf16x8*)(wb0 + kk * 32);
    const bf16x8 b1 = *(const bf16x8*)(wb1 + kk * 32);
#pragma unroll
    for (int t = 0; t < 2; ++t) {
      const int pix = (wq * 2 + t) * 16 + l15;
      bf16x8 a = *(const bf16x8*)(&abf[pix * PK + quad * 8 + kk * 32]);
      acc[t][0] = __builtin_amdgcn_mfma_f32_16x16x32_bf16(a, b0, acc[t][0], 0, 0, 0);
      acc[t][1] = __builtin_amdgcn_mfma_f32_16x16x32_bf16(a, b1, acc[t][1], 0, 0, 0);
    }
  }
#pragma unroll
  for (int t = 0; t < 2; ++t)
#pragma unroll
    for (int n = 0; n < 2; ++n) {
      const int co = n * 16 + l15;
      const float bv = pb[co];
#pragma unroll
      for (int r = 0; r < 4; ++r) {
        const int pix = (wq * 2 + t) * 16 + quad * 4 + r;
        float v = acc[t][n][r] + bv;
        v = v > 0.f ? v : 0.f;
        h0pm[((size_t)(b * 4096 + yx0 + pix)) * 32 + co] = f2bs(v);
      }
    }
}

// ---------------- 4x4 s2 p1 conv + bias + relu via MFMA, pm bf16 in/out ----------------
// OUTMODE 0: write bf16 out; OUTMODE 2: write f32 out only (ds3 identity)
template <int CIN, int COUT, int HIN, int ROWSO, int COSPLIT, int MT, int NT, int OUTMODE>
__global__ __launch_bounds__(256) void k_ds2(const short* __restrict__ inpm,
                                             const short* __restrict__ wT,
                                             const float* __restrict__ bias,
                                             short* __restrict__ outbf,
                                             float* __restrict__ outf) {
  constexpr int HOUT = HIN / 2;
  constexpr int ROWS = 2 * ROWSO + 2;
  constexpr int COLS = HIN + 2;
  constexpr int CHUNKS = CIN / 8;
  constexpr int KK = CIN / 32;
  constexpr int CIPAD = CIN + 8;
  constexpr int NHO = HOUT / ROWSO;
  __shared__ short lin[ROWS * COLS * CIPAD];
  const int tid = threadIdx.x;
  int bx = blockIdx.x;
  const int co_blk = (COSPLIT > 1) ? (bx % COSPLIT) : 0;
  if (COSPLIT > 1) bx /= COSPLIT;
  const int hoblk = bx % NHO;
  const int b = bx / NHO;
  for (int i = tid; i < ROWS * COLS * CHUNKS; i += 256) {
    const int ch = i % CHUNKS;
    const int pixv = i / CHUNKS;
    const int r = pixv / COLS, c = pixv % COLS;
    const int hi = 2 * ROWSO * hoblk - 1 + r;
    const int wc = c - 1;
    bf16x8 v = (bf16x8)(short)0;
    if (hi >= 0 && hi < HIN && wc >= 0 && wc < HIN)
      v = *(const bf16x8*)(inpm + ((size_t)(b * HIN + hi) * HIN + wc) * CIN + ch * 8);
    *(bf16x8*)(&lin[(r * COLS + c) * CIPAD + ch * 8]) = v;
  }
  __syncthreads();
  const int wq = __builtin_amdgcn_readfirstlane(tid >> 6);
  const int lane = tid & 63;
  const int l15 = lane & 15, quad = lane >> 4;
  const int mtile = (MT > 1) ? (wq % MT) : 0;
  const int cogrp = wq / MT;
  const int cobase = co_blk * (COUT / COSPLIT) + cogrp * (NT * 16);
  const int p = mtile * 16 + l15;
  const int dr = p / HOUT;
  const int col = p % HOUT;
  f32x4 acc[NT];
#pragma unroll
  for (int n = 0; n < NT; ++n) acc[n] = (f32x4){0.f, 0.f, 0.f, 0.f};
  const short* wrow = wT + (size_t)(cobase + l15) * CIN + quad * 8;
  for (int ky = 0; ky < 4; ++ky) {
    for (int kx = 0; kx < 4; ++kx) {
      const short* arow = &lin[((2 * dr + ky) * COLS + 2 * col + kx) * CIPAD + quad * 8];
      const short* wt = wrow + (size_t)(ky * 4 + kx) * COUT * CIN;
#pragma unroll
      for (int kk = 0; kk < KK; ++kk) {
        bf16x8 a = *(const bf16x8*)(arow + kk * 32);
#pragma unroll
        for (int n = 0; n < NT; ++n) {
          bf16x8 bf = *(const bf16x8*)(wt + n * 16 * CIN + kk * 32);
          acc[n] = __builtin_amdgcn_mfma_f32_16x16x32_bf16(a, bf, acc[n], 0, 0, 0);
        }
      }
    }
  }
#pragma unroll
  for (int n = 0; n < NT; ++n) {
    const int co = cobase + n * 16 + l15;
    const float bv = bias[co];
#pragma unroll
    for (int r = 0; r < 4; ++r) {
      const int pp = mtile * 16 + quad * 4 + r;
      const int dr2 = pp / HOUT;
      const int c2 = pp % HOUT;
      const int ho = hoblk * ROWSO + dr2;
      float v = acc[n][r] + bv;
      v = v > 0.f ? v : 0.f;
      const size_t o = ((size_t)b * HOUT * HOUT + ho * HOUT + c2) * COUT + co;
      if constexpr (OUTMODE != 2) outbf[o] = f2bs(v);
      else outf[o] = v;
    }
  }
}

// ================ persistent res tower: 4x(conv+BN+relu) x2 + map_skip + fc-input ================
// 64 blocks (1/image) x 512 threads (8 waves x 16 couts). All bulk data block-local; only BN
// stats cross blocks via device-scope atomics + bare monotonic counter. Weights stream from L2
// with a 3-deep register pipeline; next-phase taps are prefetched across each statsync.
__device__ __forceinline__ void statsync(unsigned* cnt, unsigned target) {
  __syncthreads();  // drains this block's stats atomics (vmcnt(0) before s_barrier)
  if (threadIdx.x == 0) {
    __hip_atomic_fetch_add(cnt, 1u, __ATOMIC_RELAXED, __HIP_MEMORY_SCOPE_AGENT);
    while (__hip_atomic_load(cnt, __ATOMIC_RELAXED, __HIP_MEMORY_SCOPE_AGENT) < target)
      __builtin_amdgcn_s_sleep(1);
  }
  __syncthreads();
}

__global__ __launch_bounds__(512) void k_res4(
    const float* __restrict__ hf32,  // ds3 f32 output [64][64pix][128]
    const short* __restrict__ wTr1, const short* __restrict__ wTr2,
    const float* __restrict__ rbn1g, const float* __restrict__ rbn1b,
    const float* __restrict__ rbn2g, const float* __restrict__ rbn2b,
    float* __restrict__ stats, unsigned* __restrict__ cnt,
    short* __restrict__ hbf, float* __restrict__ out0) {
  constexpr int CIPAD = 136;
  __shared__ short lin[100 * CIPAD];
  const int tid = threadIdx.x;
  const int b = blockIdx.x;
  const int w = __builtin_amdgcn_readfirstlane(tid >> 6);
  const int lane = tid & 63;
  const int l15 = lane & 15, quad = lane >> 4;
  const int co = w * 16 + l15;
  // zero whole tile once (border stays 0; interior overwritten each conv)
  for (int i2 = tid; i2 < 1700; i2 += 512) *(bf16x8*)(&lin[i2 * 8]) = (bf16x8)(short)0;
  // identity h and map_skip live in registers: j = m*4+r -> pixel m*16+quad*4+r, channel co
  float hloc[16], msloc[16];
  {
    const float* hf = hf32 + ((size_t)b << 13);
#pragma unroll
    for (int j = 0; j < 16; ++j) {
      const int pix = (j >> 2) * 16 + quad * 4 + (j & 3);
      const float v = hf[(size_t)pix * 128 + co];
      hloc[j] = v;
      msloc[j] = v;
    }
  }
  const size_t woff = (size_t)co * 128 + quad * 8;
  bf16x8 wb[3][4];  // 3-deep weight tap pipeline (48 VGPR)
  // preload conv1(iter0) taps 0-2
#pragma unroll
  for (int tt = 0; tt < 3; ++tt)
#pragma unroll
    for (int kk = 0; kk < 4; ++kk)
      wb[tt][kk] = *(const bf16x8*)(wTr1 + woff + (size_t)tt * 16384 + kk * 32);
  unsigned ph = 0;
  for (int i = 0; i < 4; ++i) {
    float* sA = stats + i * 512;
    float* sB = sA + 256;
    __syncthreads();  // guard lin reuse
    // stage h (bf16) into padded 10x10 tile
#pragma unroll
    for (int j = 0; j < 16; ++j) {
      const int pix = (j >> 2) * 16 + quad * 4 + (j & 3);
      const int py = pix >> 3, px = pix & 7;
      lin[((py + 1) * 10 + px + 1) * CIPAD + co] = f2bs(hloc[j]);
    }
    __syncthreads();
    // ---- conv1 (3-deep pipelined weights) ----
    f32x4 acc[4];
#pragma unroll
    for (int m = 0; m < 4; ++m) acc[m] = (f32x4){0.f, 0.f, 0.f, 0.f};
    {
      const short* base1 = wTr1 + (size_t)i * 147456 + woff;
#pragma unroll
      for (int t = 0; t < 9; ++t) {
        const int ky = t / 3, kx = t % 3;
#pragma unroll
        for (int kk = 0; kk < 4; ++kk) {
          const bf16x8 bfr = wb[t % 3][kk];
#pragma unroll
          for (int m = 0; m < 4; ++m) {
            const int pA = m * 16 + l15;
            const int py = pA >> 3, px = pA & 7;
            const bf16x8 a =
                *(const bf16x8*)(&lin[((py + ky) * 10 + px + kx) * CIPAD + quad * 8 + kk * 32]);
            acc[m] = __builtin_amdgcn_mfma_f32_16x16x32_bf16(a, bfr, acc[m], 0, 0, 0);
          }
        }
        if (t < 6) {
#pragma unroll
          for (int kk = 0; kk < 4; ++kk)
            wb[t % 3][kk] = *(const bf16x8*)(base1 + (size_t)(t + 3) * 16384 + kk * 32);
        }
      }
    }
    {
      float s = 0.f, q = 0.f;
#pragma unroll
      for (int m = 0; m < 4; ++m)
#pragma unroll
        for (int r = 0; r < 4; ++r) { const float v = acc[m][r]; s += v; q += v * v; }
      s += __shfl_down(s, 32); q += __shfl_down(q, 32);
      s += __shfl_down(s, 16); q += __shfl_down(q, 16);
      if (lane < 16) {
        atomicAdd(&sA[w * 16 + lane], s);
        atomicAdd(&sA[128 + w * 16 + lane], q);
      }
    }
    // prefetch conv2 taps 0-2 — loads complete during the statsync wait
    {
      const short* base2 = wTr2 + (size_t)i * 147456 + woff;
#pragma unroll
      for (int tt = 0; tt < 3; ++tt)
#pragma unroll
        for (int kk = 0; kk < 4; ++kk)
          wb[tt][kk] = *(const bf16x8*)(base2 + (size_t)tt * 16384 + kk * 32);
    }
    statsync(cnt, 64u * (++ph));
    // BN1 + relu, staged straight from registers
    {
      const float mu = __hip_atomic_load(&sA[co], __ATOMIC_RELAXED, __HIP_MEMORY_SCOPE_AGENT) * (1.f / 4096.f);
      const float ex2 = __hip_atomic_load(&sA[128 + co], __ATOMIC_RELAXED, __HIP_MEMORY_SCOPE_AGENT) * (1.f / 4096.f);
      const float sc1 = rbn1g[i * 128 + co] * rsqrtf(ex2 - mu * mu + 1e-5f);
      const float sh1 = rbn1b[i * 128 + co] - mu * sc1;
#pragma unroll
      for (int m = 0; m < 4; ++m)
#pragma unroll
        for (int r = 0; r < 4; ++r) {
          const int pix = m * 16 + quad * 4 + r;
          const int py = pix >> 3, px = pix & 7;
          const float v = acc[m][r] * sc1 + sh1;
          lin[((py + 1) * 10 + px + 1) * CIPAD + co] = f2bs(v > 0.f ? v : 0.f);
        }
    }
    __syncthreads();
    // ---- conv2 (3-deep pipelined weights) ----
#pragma unroll
    for (int m = 0; m < 4; ++m) acc[m] = (f32x4){0.f, 0.f, 0.f, 0.f};
    {
      const short* base2 = wTr2 + (size_t)i * 147456 + woff;
#pragma unroll
      for (int t = 0; t < 9; ++t) {
        const int ky = t / 3, kx = t % 3;
#pragma unroll
        for (int kk = 0; kk < 4; ++kk) {
          const bf16x8 bfr = wb[t % 3][kk];
#pragma unroll
          for (int m = 0; m < 4; ++m) {
            const int pA = m * 16 + l15;
            const int py = pA >> 3, px = pA & 7;
            const bf16x8 a =
                *(const bf16x8*)(&lin[((py + ky) * 10 + px + kx) * CIPAD + quad * 8 + kk * 32]);
            acc[m] = __builtin_amdgcn_mfma_f32_16x16x32_bf16(a, bfr, acc[m], 0, 0, 0);
          }
        }
        if (t < 6) {
#pragma unroll
          for (int kk = 0; kk < 4; ++kk)
            wb[t % 3][kk] = *(const bf16x8*)(base2 + (size_t)(t + 3) * 16384 + kk * 32);
        }
      }
    }
    {
      float s = 0.f, q = 0.f;
#pragma unroll
      for (int m = 0; m < 4; ++m)
#pragma unroll
        for (int r = 0; r < 4; ++r) { const float v = acc[m][r]; s += v; q += v * v; }
      s += __shfl_down(s, 32); q += __shfl_down(q, 32);
      s += __shfl_down(s, 16); q += __shfl_down(q, 16);
      if (lane < 16) {
        atomicAdd(&sB[w * 16 + lane], s);
        atomicAdd(&sB[128 + w * 16 + lane], q);
      }
    }
    // prefetch next-iter conv1 taps 0-2 across the statsync
    if (i < 3) {
      const short* base1n = wTr1 + (size_t)(i + 1) * 147456 + woff;
#pragma unroll
      for (int tt = 0; tt < 3; ++tt)
#pragma unroll
        for (int kk = 0; kk < 4; ++kk)
          wb[tt][kk] = *(const bf16x8*)(base1n + (size_t)tt * 16384 + kk * 32);
    }
    statsync(cnt, 64u * (++ph));
    // BN2 + identity + relu + map_skip, all in registers
    {
      const float mu = __hip_atomic_load(&sB[co], __ATOMIC_RELAXED, __HIP_MEMORY_SCOPE_AGENT) * (1.f / 4096.f);
      const float ex2 = __hip_atomic_load(&sB[128 + co], __ATOMIC_RELAXED, __HIP_MEMORY_SCOPE_AGENT) * (1.f / 4096.f);
      const float sc2 = rbn2g[i * 128 + co] * rsqrtf(ex2 - mu * mu + 1e-5f);
      const float sh2 = rbn2b[i * 128 + co] - mu * sc2;
#pragma unroll
      for (int m = 0; m < 4; ++m)
#pragma unroll
        for (int r = 0; r < 4; ++r) {
          float v = acc[m][r] * sc2 + sh2 + hloc[m * 4 + r];
          v = v > 0.f ? v : 0.f;
          hloc[m * 4 + r] = v;
          msloc[m * 4 + r] += v;
        }
    }
  }
  // epilogue: map_skip canonical [b][co][pix] + fc input bf16 [b][pix*128+co]
  {
    float* ob = out0 + ((size_t)b << 13) + (size_t)co * 64;
    short* hb = hbf + ((size_t)b << 13);
#pragma unroll
    for (int j = 0; j < 16; ++j) {
      const int pix = (j >> 2) * 16 + quad * 4 + (j & 3);
      ob[pix] = msloc[j];
      hb[(size_t)pix * 128 + co] = f2bs(hloc[j]);
    }
  }
}

// ---------------- FC via MFMA: k-split partials ----------------
__global__ __launch_bounds__(256) void k_fcmfma(const short* __restrict__ hbf,
                                                const short* __restrict__ wbf,
                                                float* __restrict__ part) {
  const int nb = blockIdx.x & 3;
  const int kb = blockIdx.x >> 2;
  const int wq = __builtin_amdgcn_readfirstlane((int)(threadIdx.x >> 6));
  const int lane = threadIdx.x & 63;
  const int l15 = lane & 15, quad = lane >> 4;
  const int k0 = kb * 256 + quad * 8;
  const short* wp = wbf + (size_t)(nb * 64 + wq * 16 + l15) * 8192 + k0;
  const short* hp = hbf + (size_t)l15 * 8192 + k0;
  f32x4 acc[4];
#pragma unroll
  for (int m = 0; m < 4; ++m) acc[m] = (f32x4){0.f, 0.f, 0.f, 0.f};
  for (int ks = 0; ks < 8; ++ks) {
    bf16x8 bfr = *(const bf16x8*)(wp + ks * 32);
#pragma unroll
    for (int m = 0; m < 4; ++m) {
      bf16x8 a = *(const bf16x8*)(hp + (size_t)m * 16 * 8192 + ks * 32);
      acc[m] = __builtin_amdgcn_mfma_f32_16x16x32_bf16(a, bfr, acc[m], 0, 0, 0);
    }
  }
#pragma unroll
  for (int m = 0; m < 4; ++m)
#pragma unroll
    for (int r = 0; r < 4; ++r) {
      const int b = m * 16 + quad * 4 + r;
      part[((size_t)kb * 64 + b) * 256 + nb * 64 + wq * 16 + l15] = acc[m][r];
    }
}

__global__ __launch_bounds__(256) void k_fcred(const float* __restrict__ part,
                                               const float* __restrict__ bias,
                                               float* __restrict__ out1) {
  const int idx = blockIdx.x * 256 + threadIdx.x;
  const int j = idx & 255;
  float s = 0.f;
#pragma unroll 8
  for (int kb = 0; kb < 32; ++kb) s += part[(size_t)kb * 16384 + idx];
  const float v = s + bias[j];
  out1[idx] = v > 0.f ? v : 0.f;
}

extern "C" void kernel_launch(void* const* d_in, const int* in_sizes, int n_in,
                              void* d_out, int out_size, void* d_ws, size_t ws_size,
                              hipStream_t stream) {
  const float* xin = (const float*)d_in[0];
  const float* emb = (const float*)d_in[1];
  const int* xy = (const int*)d_in[2];
  const float* c1w = (const float*)d_in[3];
  const float* pw = (const float*)d_in[4];
  const float* pb = (const float*)d_in[5];
  const float* d1w = (const float*)d_in[6];
  const float* d1b = (const float*)d_in[7];
  const float* d2w = (const float*)d_in[8];
  const float* d2b = (const float*)d_in[9];
  const float* d3w = (const float*)d_in[10];
  const float* d3b = (const float*)d_in[11];
  const float* rc1w = (const float*)d_in[12];
  const float* rbn1g = (const float*)d_in[13];
  const float* rbn1b = (const float*)d_in[14];
  const float* rc2w = (const float*)d_in[15];
  const float* rbn2g = (const float*)d_in[16];
  const float* rbn2b = (const float*)d_in[17];
  const float* fcw = (const float*)d_in[18];
  const float* fcb = (const float*)d_in[19];

  float* out0 = (float*)d_out;   // map_skip [64,128,8,8] f32
  float* out1 = out0 + 524288;   // embedded_spatial [64,256] f32

  float* F = (float*)d_ws;
  float* scat = F + 0;                    // [64][4096][32] f32 — dead after projmfma; reused:
  short* h1pm = (short*)(F + 0);          // [64][32][32][64] bf16
  short* h2pm = (short*)(F + 2097152);    // [64][16][16][128] bf16
  float* hf32 = F + 3145728;              // ds3 f32 identity [64][64][128]
  short* hbf = (short*)(F + 5242880);     // final h bf16 (fc input)
  float* stats = F + 6291456;             // 4 layers x 512 + counter + pad (zeroed 2064)
  unsigned* cnt = (unsigned*)(stats + 2048);
  float* fcpart = F + 6293504;            // 32 x [64][256] f32, ends 6817792 < 8388608
  short* h0pm = (short*)(F + 8388608);    // [64][4096][32] bf16
  short* wfcbf = (short*)(F + 12582912);
  short* wTr1 = (short*)(F + 13631488);
  short* wTr2 = wTr1 + 589824;
  short* wTds1 = wTr2 + 589824;
  short* wTds2 = wTds1 + 32768;
  short* wTds3 = wTds2 + 131072;
  short* wsc = wTds3 + 262144;            // 8192 shorts
  short* wproj = wsc + 8192;              // 2048 shorts

  k_wall<<<1425, 256, 0, stream>>>(rc1w, rc2w, d1w, d2w, d3w, fcw, c1w, pw,
                                   wTr1, wTr2, wTds1, wTds2, wTds3, wfcbf, wsc, wproj,
                                   scat, stats);
  k_scatmfma<<<512, 256, 0, stream>>>(emb, xy, wsc, scat);
  k_projmfma<<<2048, 256, 0, stream>>>(scat, xin, wproj, pb, h0pm);
  k_ds2<32, 64, 64, 2, 1, 4, 4, 0><<<1024, 256, 0, stream>>>(h0pm, wTds1, d1b, h1pm, nullptr);
  k_ds2<64, 128, 32, 1, 1, 1, 2, 0><<<1024, 256, 0, stream>>>(h1pm, wTds2, d2b, h2pm, nullptr);
  k_ds2<128, 128, 16, 2, 2, 1, 1, 2><<<512, 256, 0, stream>>>(h2pm, wTds3, d3b, nullptr, hf32);
  k_res4<<<64, 512, 0, stream>>>(hf32, wTr1, wTr2, rbn1g, rbn1b, rbn2g, rbn2b,
                                 stats, cnt, hbf, out0);
  k_fcmfma<<<128, 256, 0, stream>>>(hbf, wfcbf, fcpart);
  k_fcred<<<64, 256, 0, stream>>>(fcpart, fcb, out1);
}

// Round 10
// 342.093 us; speedup vs baseline: 1.2343x; 1.0822x over previous
//
#include <hip/hip_runtime.h>
#include <hip/hip_bf16.h>

typedef __attribute__((ext_vector_type(8))) short bf16x8;  // 8 bf16 (4 VGPRs)
typedef __attribute__((ext_vector_type(4))) short bf16x4;
typedef __attribute__((ext_vector_type(4))) float f32x4;   // MFMA C/D frag

__device__ __forceinline__ short f2bs(float v) {
  __hip_bfloat16 h = __float2bfloat16(v);
  return *reinterpret_cast<short*>(&h);
}

// ================ fused weight transforms + workspace zeroing (one launch) ================
// [0,512) res weights (LDS-coalesced) | [512,616) ds weights (LDS-coalesced)
// [616,872) fc | [872,904) scat w | [904,912) proj w | [912,1424) zero scat | 1424 zero stats
__global__ __launch_bounds__(256) void k_wall(
    const float* __restrict__ rc1w, const float* __restrict__ rc2w,
    const float* __restrict__ d1w, const float* __restrict__ d2w,
    const float* __restrict__ d3w, const float* __restrict__ fcw,
    const float* __restrict__ c1w, const float* __restrict__ pw,
    short* __restrict__ wTr1, short* __restrict__ wTr2, short* __restrict__ wTds1,
    short* __restrict__ wTds2, short* __restrict__ wTds3, short* __restrict__ wfcbf,
    short* __restrict__ wsc, short* __restrict__ wproj,
    float* __restrict__ scatz, float* __restrict__ statsz) {
  __shared__ float ld[128 * 65];
  const int bx = blockIdx.x;
  const int tid = threadIdx.x;
  if (bx < 512) {  // res-conv weights: [l][co][ci][3][3] -> [l][tap][co][ci]
    const float* src = (bx < 256) ? rc1w : rc2w;
    short* dst = (bx < 256) ? wTr1 : wTr2;
    const int cb = bx & 255;
    const float* sp = src + (size_t)cb * 2304;
#pragma unroll
    for (int r = 0; r < 9; ++r) ld[r * 256 + tid] = sp[r * 256 + tid];
    __syncthreads();
    const int g = cb * 256 + tid;  // global (layer,co,ci) index in [0,65536)
    const int layer = g >> 14, win = g & 16383;
    short* dp = dst + (size_t)layer * 147456 + win;
#pragma unroll
    for (int k = 0; k < 9; ++k) dp[k * 16384] = f2bs(ld[tid * 9 + k]);
  } else if (bx < 616) {  // ds weights: [co][ci][16taps] -> [tap][co][ci]
    int base, COCI;
    const float* src;
    short* dst;
    if (bx < 520) { base = 512; COCI = 2048; src = d1w; dst = wTds1; }
    else if (bx < 552) { base = 520; COCI = 8192; src = d2w; dst = wTds2; }
    else { base = 552; COCI = 16384; src = d3w; dst = wTds3; }
    const int cb = bx - base;
    const float* sp = src + (size_t)cb * 4096;
#pragma unroll
    for (int r = 0; r < 16; ++r) {
      const int j = r * 256 + tid;
      ld[j + (j >> 4)] = sp[j];  // pad to stride-17 rows (gcd(17,32)=1)
    }
    __syncthreads();
    const int g = cb * 256 + tid;
    short* dp = dst + g;
#pragma unroll
    for (int k = 0; k < 16; ++k) dp[(size_t)k * COCI] = f2bs(ld[tid * 17 + k]);
  } else if (bx < 872) {  // fc: [j][co*64+pix] -> [j][pix*128+co]
    const int j = bx - 616;
    const float* sp = fcw + (size_t)j * 8192;
    for (int i = tid; i < 8192; i += 256) {
      const int co = i >> 6, pix = i & 63;
      ld[co * 65 + pix] = sp[i];
    }
    __syncthreads();
    short* dp = wfcbf + (size_t)j * 8192;
    for (int i = tid; i < 8192; i += 256) {
      const int pix = i >> 7, co = i & 127;
      dp[i] = f2bs(ld[co * 65 + pix]);
    }
  } else if (bx < 904) {  // scatter weight: [co][ci] f32 -> bf16
    const int i = (bx - 872) * 256 + tid;
    if (i < 8192) wsc[i] = f2bs(c1w[i]);
  } else if (bx < 912) {  // project weight: [co][50] -> [co][64] zero-padded
    const int i = (bx - 904) * 256 + tid;
    if (i < 2048) {
      const int co = i >> 6, k = i & 63;
      wproj[i] = (k < 50) ? f2bs(pw[co * 50 + k]) : (short)0;
    }
  } else if (bx < 1424) {  // zero scat (8M floats over 512 blocks)
    float4* dst = (float4*)(scatz + (size_t)(bx - 912) * 16384);
    const float4 z = {0.f, 0.f, 0.f, 0.f};
    for (int t = tid; t < 4096; t += 256) dst[t] = z;
  } else {  // zero stats + barrier counter + pad
    for (int i = tid; i < 2064; i += 256) statsz[i] = 0.f;
  }
}

// ================ scatter: entity GEMM (MFMA) + relu + scatter-add ================
__global__ __launch_bounds__(256) void k_scatmfma(const float* __restrict__ emb,
                                                  const int* __restrict__ xy,
                                                  const short* __restrict__ wsc,
                                                  float* __restrict__ scat_pm) {
  constexpr int CIP = 264;
  __shared__ short abf[64 * CIP];
  __shared__ int flat[64];
  const int tid = threadIdx.x;
  const int e0 = blockIdx.x * 64;
  const float4* eg = (const float4*)(emb + (size_t)e0 * 256);
  for (int i = tid; i < 4096; i += 256) {
    const int e = i >> 6, k4 = i & 63;
    const float4 v = eg[(size_t)e * 64 + k4];
    bf16x4 o;
    o[0] = f2bs(v.x); o[1] = f2bs(v.y); o[2] = f2bs(v.z); o[3] = f2bs(v.w);
    *(bf16x4*)(&abf[e * CIP + k4 * 4]) = o;
  }
  if (tid < 64) {
    const int* bp = xy + (size_t)(e0 + tid) * 16;
    int xv = 0, yv = 0;
#pragma unroll
    for (int j = 0; j < 8; ++j) xv = (xv << 1) | bp[j];
#pragma unroll
    for (int j = 8; j < 16; ++j) yv = (yv << 1) | bp[j];
    flat[tid] = (bp[0] != -1000000000)
                    ? (((e0 + tid) >> 9) * 4096 + ((yv >> 2) << 6) + (xv >> 2))
                    : -1;
  }
  __syncthreads();
  const int wq = __builtin_amdgcn_readfirstlane(tid >> 6);
  const int lane = tid & 63;
  const int l15 = lane & 15, quad = lane >> 4;
  f32x4 acc[2];
  acc[0] = (f32x4){0.f, 0.f, 0.f, 0.f};
  acc[1] = (f32x4){0.f, 0.f, 0.f, 0.f};
  const short* arow = &abf[(wq * 16 + l15) * CIP + quad * 8];
  const short* w0 = wsc + (size_t)l15 * 256 + quad * 8;
  const short* w1 = wsc + (size_t)(16 + l15) * 256 + quad * 8;
#pragma unroll
  for (int kk = 0; kk < 8; ++kk) {
    bf16x8 a = *(const bf16x8*)(arow + kk * 32);
    acc[0] = __builtin_amdgcn_mfma_f32_16x16x32_bf16(a, *(const bf16x8*)(w0 + kk * 32), acc[0], 0, 0, 0);
    acc[1] = __builtin_amdgcn_mfma_f32_16x16x32_bf16(a, *(const bf16x8*)(w1 + kk * 32), acc[1], 0, 0, 0);
  }
#pragma unroll
  for (int nt = 0; nt < 2; ++nt)
#pragma unroll
    for (int r = 0; r < 4; ++r) {
      const int e = wq * 16 + quad * 4 + r;
      const float v = acc[nt][r];
      const int f = flat[e];
      if (f >= 0 && v > 0.f)
        atomicAdd(&scat_pm[(size_t)f * 32 + nt * 16 + l15], v);
    }
}

// ================ project: concat + 1x1 conv + relu via MFMA -> pm bf16 ================
__global__ __launch_bounds__(256) void k_projmfma(const float* __restrict__ scat_pm,
                                                  const float* __restrict__ xin,
                                                  const short* __restrict__ wproj,
                                                  const float* __restrict__ pb,
                                                  short* __restrict__ h0pm) {
  constexpr int PK = 72;
  __shared__ short abf[128 * PK];
  const int tid = threadIdx.x;
  const int b = blockIdx.x >> 5;
  const int yx0 = (blockIdx.x & 31) << 7;
  const float4* sg = (const float4*)(scat_pm + ((size_t)(b * 4096 + yx0)) * 32);
  for (int i = tid; i < 1024; i += 256) {
    const int p = i >> 3, c4 = i & 7;
    const float4 v = sg[(size_t)p * 8 + c4];
    bf16x4 o;
    o[0] = f2bs(v.x); o[1] = f2bs(v.y); o[2] = f2bs(v.z); o[3] = f2bs(v.w);
    *(bf16x4*)(&abf[p * PK + c4 * 4]) = o;
  }
  for (int i = tid; i < 2304; i += 256) {
    const int run = i >> 7, p = i & 127;
    abf[p * PK + 32 + run] = f2bs(xin[(size_t)(b * 18 + run) * 4096 + yx0 + p]);
  }
  for (int i = tid; i < 2048; i += 256) {
    const int p = i >> 4, k = 50 + (i & 15);
    abf[p * PK + k] = 0;
  }
  __syncthreads();
  const int wq = __builtin_amdgcn_readfirstlane(tid >> 6);
  const int lane = tid & 63;
  const int l15 = lane & 15, quad = lane >> 4;
  f32x4 acc[2][2];
#pragma unroll
  for (int t = 0; t < 2; ++t)
#pragma unroll
    for (int n = 0; n < 2; ++n) acc[t][n] = (f32x4){0.f, 0.f, 0.f, 0.f};
  const short* wb0 = wproj + (size_t)l15 * 64 + quad * 8;
  const short* wb1 = wproj + (size_t)(16 + l15) * 64 + quad * 8;
#pragma unroll
  for (int kk = 0; kk < 2; ++kk) {
    const bf16x8 b0 = *(const bf16x8*)(wb0 + kk * 32);
    const bf16x8 b1 = *(const bf16x8*)(wb1 + kk * 32);
#pragma unroll
    for (int t = 0; t < 2; ++t) {
      const int pix = (wq * 2 + t) * 16 + l15;
      bf16x8 a = *(const bf16x8*)(&abf[pix * PK + quad * 8 + kk * 32]);
      acc[t][0] = __builtin_amdgcn_mfma_f32_16x16x32_bf16(a, b0, acc[t][0], 0, 0, 0);
      acc[t][1] = __builtin_amdgcn_mfma_f32_16x16x32_bf16(a, b1, acc[t][1], 0, 0, 0);
    }
  }
#pragma unroll
  for (int t = 0; t < 2; ++t)
#pragma unroll
    for (int n = 0; n < 2; ++n) {
      const int co = n * 16 + l15;
      const float bv = pb[co];
#pragma unroll
      for (int r = 0; r < 4; ++r) {
        const int pix = (wq * 2 + t) * 16 + quad * 4 + r;
        float v = acc[t][n][r] + bv;
        v = v > 0.f ? v : 0.f;
        h0pm[((size_t)(b * 4096 + yx0 + pix)) * 32 + co] = f2bs(v);
      }
    }
}

// ---------------- 4x4 s2 p1 conv + bias + relu via MFMA, pm bf16 in/out ----------------
// OUTMODE 0: write bf16 out; OUTMODE 2: write f32 out only (ds3 identity)
template <int CIN, int COUT, int HIN, int ROWSO, int COSPLIT, int MT, int NT, int OUTMODE>
__global__ __launch_bounds__(256) void k_ds2(const short* __restrict__ inpm,
                                             const short* __restrict__ wT,
                                             const float* __restrict__ bias,
                                             short* __restrict__ outbf,
                                             float* __restrict__ outf) {
  constexpr int HOUT = HIN / 2;
  constexpr int ROWS = 2 * ROWSO + 2;
  constexpr int COLS = HIN + 2;
  constexpr int CHUNKS = CIN / 8;
  constexpr int KK = CIN / 32;
  constexpr int CIPAD = CIN + 8;
  constexpr int NHO = HOUT / ROWSO;
  __shared__ short lin[ROWS * COLS * CIPAD];
  const int tid = threadIdx.x;
  int bx = blockIdx.x;
  const int co_blk = (COSPLIT > 1) ? (bx % COSPLIT) : 0;
  if (COSPLIT > 1) bx /= COSPLIT;
  const int hoblk = bx % NHO;
  const int b = bx / NHO;
  for (int i = tid; i < ROWS * COLS * CHUNKS; i += 256) {
    const int ch = i % CHUNKS;
    const int pixv = i / CHUNKS;
    const int r = pixv / COLS, c = pixv % COLS;
    const int hi = 2 * ROWSO * hoblk - 1 + r;
    const int wc = c - 1;
    bf16x8 v = (bf16x8)(short)0;
    if (hi >= 0 && hi < HIN && wc >= 0 && wc < HIN)
      v = *(const bf16x8*)(inpm + ((size_t)(b * HIN + hi) * HIN + wc) * CIN + ch * 8);
    *(bf16x8*)(&lin[(r * COLS + c) * CIPAD + ch * 8]) = v;
  }
  __syncthreads();
  const int wq = __builtin_amdgcn_readfirstlane(tid >> 6);
  const int lane = tid & 63;
  const int l15 = lane & 15, quad = lane >> 4;
  const int mtile = (MT > 1) ? (wq % MT) : 0;
  const int cogrp = wq / MT;
  const int cobase = co_blk * (COUT / COSPLIT) + cogrp * (NT * 16);
  const int p = mtile * 16 + l15;
  const int dr = p / HOUT;
  const int col = p % HOUT;
  f32x4 acc[NT];
#pragma unroll
  for (int n = 0; n < NT; ++n) acc[n] = (f32x4){0.f, 0.f, 0.f, 0.f};
  const short* wrow = wT + (size_t)(cobase + l15) * CIN + quad * 8;
  for (int ky = 0; ky < 4; ++ky) {
    for (int kx = 0; kx < 4; ++kx) {
      const short* arow = &lin[((2 * dr + ky) * COLS + 2 * col + kx) * CIPAD + quad * 8];
      const short* wt = wrow + (size_t)(ky * 4 + kx) * COUT * CIN;
#pragma unroll
      for (int kk = 0; kk < KK; ++kk) {
        bf16x8 a = *(const bf16x8*)(arow + kk * 32);
#pragma unroll
        for (int n = 0; n < NT; ++n) {
          bf16x8 bf = *(const bf16x8*)(wt + n * 16 * CIN + kk * 32);
          acc[n] = __builtin_amdgcn_mfma_f32_16x16x32_bf16(a, bf, acc[n], 0, 0, 0);
        }
      }
    }
  }
#pragma unroll
  for (int n = 0; n < NT; ++n) {
    const int co = cobase + n * 16 + l15;
    const float bv = bias[co];
#pragma unroll
    for (int r = 0; r < 4; ++r) {
      const int pp = mtile * 16 + quad * 4 + r;
      const int dr2 = pp / HOUT;
      const int c2 = pp % HOUT;
      const int ho = hoblk * ROWSO + dr2;
      float v = acc[n][r] + bv;
      v = v > 0.f ? v : 0.f;
      const size_t o = ((size_t)b * HOUT * HOUT + ho * HOUT + c2) * COUT + co;
      if constexpr (OUTMODE != 2) outbf[o] = f2bs(v);
      else outf[o] = v;
    }
  }
}

// ================ persistent res tower: 4x(conv+BN+relu) x2 + map_skip + fc-input ================
// 64 blocks (1/image) x 512 threads (8 waves x 16 couts = 128 ch). All bulk data block-local;
// only BN stats cross blocks, via device-scope atomics + a bare monotonic counter.
__device__ __forceinline__ void statsync(unsigned* cnt, unsigned target) {
  __syncthreads();  // drains this block's stats atomics (vmcnt(0) before s_barrier)
  if (threadIdx.x == 0) {
    __hip_atomic_fetch_add(cnt, 1u, __ATOMIC_RELAXED, __HIP_MEMORY_SCOPE_AGENT);
    while (__hip_atomic_load(cnt, __ATOMIC_RELAXED, __HIP_MEMORY_SCOPE_AGENT) < target)
      __builtin_amdgcn_s_sleep(1);
  }
  __syncthreads();
}

__global__ __launch_bounds__(512) void k_res4(
    const float* __restrict__ hf32,  // ds3 f32 output [64][64pix][128]
    const short* __restrict__ wTr1, const short* __restrict__ wTr2,
    const float* __restrict__ rbn1g, const float* __restrict__ rbn1b,
    const float* __restrict__ rbn2g, const float* __restrict__ rbn2b,
    float* __restrict__ stats, unsigned* __restrict__ cnt,
    short* __restrict__ hbf, float* __restrict__ out0) {
  constexpr int CIPAD = 136;
  __shared__ short lin[100 * CIPAD];
  const int tid = threadIdx.x;
  const int b = blockIdx.x;
  const int w = __builtin_amdgcn_readfirstlane(tid >> 6);
  const int lane = tid & 63;
  const int l15 = lane & 15, quad = lane >> 4;
  const int co = w * 16 + l15;
  // zero whole tile once (border stays 0; interior overwritten each conv)
  for (int i2 = tid; i2 < 1700; i2 += 512) *(bf16x8*)(&lin[i2 * 8]) = (bf16x8)(short)0;
  // identity h and map_skip live in registers: j = m*4+r -> pixel m*16+quad*4+r, channel co
  float hloc[16], msloc[16];
  {
    const float* hf = hf32 + ((size_t)b << 13);
#pragma unroll
    for (int j = 0; j < 16; ++j) {
      const int pix = (j >> 2) * 16 + quad * 4 + (j & 3);
      const float v = hf[(size_t)pix * 128 + co];
      hloc[j] = v;
      msloc[j] = v;
    }
  }
  unsigned ph = 0;
  for (int i = 0; i < 4; ++i) {
    float* sA = stats + i * 512;
    float* sB = sA + 256;
    __syncthreads();  // guard lin reuse (zero-init on iter 0; prev conv2 reads done via statsync)
    // stage h (bf16) into padded 10x10 tile
#pragma unroll
    for (int j = 0; j < 16; ++j) {
      const int pix = (j >> 2) * 16 + quad * 4 + (j & 3);
      const int py = pix >> 3, px = pix & 7;
      lin[((py + 1) * 10 + px + 1) * CIPAD + co] = f2bs(hloc[j]);
    }
    __syncthreads();
    // ---- conv1 ----
    f32x4 acc[4];
#pragma unroll
    for (int m = 0; m < 4; ++m) acc[m] = (f32x4){0.f, 0.f, 0.f, 0.f};
    {
      const short* wrow = wTr1 + (size_t)i * 147456 + (size_t)co * 128 + quad * 8;
      for (int t = 0; t < 9; ++t) {
        const int ky = t / 3, kx = t % 3;
        const short* wt = wrow + (size_t)t * 16384;
#pragma unroll
        for (int kk = 0; kk < 4; ++kk) {
          const bf16x8 bfr = *(const bf16x8*)(wt + kk * 32);
#pragma unroll
          for (int m = 0; m < 4; ++m) {
            const int pA = m * 16 + l15;
            const int py = pA >> 3, px = pA & 7;
            const bf16x8 a =
                *(const bf16x8*)(&lin[((py + ky) * 10 + px + kx) * CIPAD + quad * 8 + kk * 32]);
            acc[m] = __builtin_amdgcn_mfma_f32_16x16x32_bf16(a, bfr, acc[m], 0, 0, 0);
          }
        }
      }
    }
    {
      float s = 0.f, q = 0.f;
#pragma unroll
      for (int m = 0; m < 4; ++m)
#pragma unroll
        for (int r = 0; r < 4; ++r) { const float v = acc[m][r]; s += v; q += v * v; }
      s += __shfl_down(s, 32); q += __shfl_down(q, 32);
      s += __shfl_down(s, 16); q += __shfl_down(q, 16);
      if (lane < 16) {
        atomicAdd(&sA[w * 16 + lane], s);
        atomicAdd(&sA[128 + w * 16 + lane], q);
      }
    }
    statsync(cnt, 64u * (++ph));
    // BN1 + relu, staged straight from registers (no global round-trip)
    {
      const float mu = __hip_atomic_load(&sA[co], __ATOMIC_RELAXED, __HIP_MEMORY_SCOPE_AGENT) * (1.f / 4096.f);
      const float ex2 = __hip_atomic_load(&sA[128 + co], __ATOMIC_RELAXED, __HIP_MEMORY_SCOPE_AGENT) * (1.f / 4096.f);
      const float sc1 = rbn1g[i * 128 + co] * rsqrtf(ex2 - mu * mu + 1e-5f);
      const float sh1 = rbn1b[i * 128 + co] - mu * sc1;
#pragma unroll
      for (int m = 0; m < 4; ++m)
#pragma unroll
        for (int r = 0; r < 4; ++r) {
          const int pix = m * 16 + quad * 4 + r;
          const int py = pix >> 3, px = pix & 7;
          const float v = acc[m][r] * sc1 + sh1;
          lin[((py + 1) * 10 + px + 1) * CIPAD + co] = f2bs(v > 0.f ? v : 0.f);
        }
    }
    __syncthreads();
    // ---- conv2 ----
#pragma unroll
    for (int m = 0; m < 4; ++m) acc[m] = (f32x4){0.f, 0.f, 0.f, 0.f};
    {
      const short* wrow = wTr2 + (size_t)i * 147456 + (size_t)co * 128 + quad * 8;
      for (int t = 0; t < 9; ++t) {
        const int ky = t / 3, kx = t % 3;
        const short* wt = wrow + (size_t)t * 16384;
#pragma unroll
        for (int kk = 0; kk < 4; ++kk) {
          const bf16x8 bfr = *(const bf16x8*)(wt + kk * 32);
#pragma unroll
          for (int m = 0; m < 4; ++m) {
            const int pA = m * 16 + l15;
            const int py = pA >> 3, px = pA & 7;
            const bf16x8 a =
                *(const bf16x8*)(&lin[((py + ky) * 10 + px + kx) * CIPAD + quad * 8 + kk * 32]);
            acc[m] = __builtin_amdgcn_mfma_f32_16x16x32_bf16(a, bfr, acc[m], 0, 0, 0);
          }
        }
      }
    }
    {
      float s = 0.f, q = 0.f;
#pragma unroll
      for (int m = 0; m < 4; ++m)
#pragma unroll
        for (int r = 0; r < 4; ++r) { const float v = acc[m][r]; s += v; q += v * v; }
      s += __shfl_down(s, 32); q += __shfl_down(q, 32);
      s += __shfl_down(s, 16); q += __shfl_down(q, 16);
      if (lane < 16) {
        atomicAdd(&sB[w * 16 + lane], s);
        atomicAdd(&sB[128 + w * 16 + lane], q);
      }
    }
    statsync(cnt, 64u * (++ph));
    // BN2 + identity + relu + map_skip, all in registers
    {
      const float mu = __hip_atomic_load(&sB[co], __ATOMIC_RELAXED, __HIP_MEMORY_SCOPE_AGENT) * (1.f / 4096.f);
      const float ex2 = __hip_atomic_load(&sB[128 + co], __ATOMIC_RELAXED, __HIP_MEMORY_SCOPE_AGENT) * (1.f / 4096.f);
      const float sc2 = rbn2g[i * 128 + co] * rsqrtf(ex2 - mu * mu + 1e-5f);
      const float sh2 = rbn2b[i * 128 + co] - mu * sc2;
#pragma unroll
      for (int m = 0; m < 4; ++m)
#pragma unroll
        for (int r = 0; r < 4; ++r) {
          float v = acc[m][r] * sc2 + sh2 + hloc[m * 4 + r];
          v = v > 0.f ? v : 0.f;
          hloc[m * 4 + r] = v;
          msloc[m * 4 + r] += v;
        }
    }
  }
  // epilogue: map_skip canonical [b][co][pix] + fc input bf16 [b][pix*128+co]
  {
    float* ob = out0 + ((size_t)b << 13) + (size_t)co * 64;
    short* hb = hbf + ((size_t)b << 13);
#pragma unroll
    for (int j = 0; j < 16; ++j) {
      const int pix = (j >> 2) * 16 + quad * 4 + (j & 3);
      ob[pix] = msloc[j];
      hb[(size_t)pix * 128 + co] = f2bs(hloc[j]);
    }
  }
}

// ---------------- FC via MFMA: k-split partials ----------------
__global__ __launch_bounds__(256) void k_fcmfma(const short* __restrict__ hbf,
                                                const short* __restrict__ wbf,
                                                float* __restrict__ part) {
  const int nb = blockIdx.x & 3;
  const int kb = blockIdx.x >> 2;
  const int wq = __builtin_amdgcn_readfirstlane((int)(threadIdx.x >> 6));
  const int lane = threadIdx.x & 63;
  const int l15 = lane & 15, quad = lane >> 4;
  const int k0 = kb * 256 + quad * 8;
  const short* wp = wbf + (size_t)(nb * 64 + wq * 16 + l15) * 8192 + k0;
  const short* hp = hbf + (size_t)l15 * 8192 + k0;
  f32x4 acc[4];
#pragma unroll
  for (int m = 0; m < 4; ++m) acc[m] = (f32x4){0.f, 0.f, 0.f, 0.f};
  for (int ks = 0; ks < 8; ++ks) {
    bf16x8 bfr = *(const bf16x8*)(wp + ks * 32);
#pragma unroll
    for (int m = 0; m < 4; ++m) {
      bf16x8 a = *(const bf16x8*)(hp + (size_t)m * 16 * 8192 + ks * 32);
      acc[m] = __builtin_amdgcn_mfma_f32_16x16x32_bf16(a, bfr, acc[m], 0, 0, 0);
    }
  }
#pragma unroll
  for (int m = 0; m < 4; ++m)
#pragma unroll
    for (int r = 0; r < 4; ++r) {
      const int b = m * 16 + quad * 4 + r;
      part[((size_t)kb * 64 + b) * 256 + nb * 64 + wq * 16 + l15] = acc[m][r];
    }
}

__global__ __launch_bounds__(256) void k_fcred(const float* __restrict__ part,
                                               const float* __restrict__ bias,
                                               float* __restrict__ out1) {
  const int idx = blockIdx.x * 256 + threadIdx.x;
  const int j = idx & 255;
  float s = 0.f;
#pragma unroll 8
  for (int kb = 0; kb < 32; ++kb) s += part[(size_t)kb * 16384 + idx];
  const float v = s + bias[j];
  out1[idx] = v > 0.f ? v : 0.f;
}

extern "C" void kernel_launch(void* const* d_in, const int* in_sizes, int n_in,
                              void* d_out, int out_size, void* d_ws, size_t ws_size,
                              hipStream_t stream) {
  const float* xin = (const float*)d_in[0];
  const float* emb = (const float*)d_in[1];
  const int* xy = (const int*)d_in[2];
  const float* c1w = (const float*)d_in[3];
  const float* pw = (const float*)d_in[4];
  const float* pb = (const float*)d_in[5];
  const float* d1w = (const float*)d_in[6];
  const float* d1b = (const float*)d_in[7];
  const float* d2w = (const float*)d_in[8];
  const float* d2b = (const float*)d_in[9];
  const float* d3w = (const float*)d_in[10];
  const float* d3b = (const float*)d_in[11];
  const float* rc1w = (const float*)d_in[12];
  const float* rbn1g = (const float*)d_in[13];
  const float* rbn1b = (const float*)d_in[14];
  const float* rc2w = (const float*)d_in[15];
  const float* rbn2g = (const float*)d_in[16];
  const float* rbn2b = (const float*)d_in[17];
  const float* fcw = (const float*)d_in[18];
  const float* fcb = (const float*)d_in[19];

  float* out0 = (float*)d_out;   // map_skip [64,128,8,8] f32
  float* out1 = out0 + 524288;   // embedded_spatial [64,256] f32

  float* F = (float*)d_ws;
  float* scat = F + 0;                    // [64][4096][32] f32 — dead after projmfma; reused:
  short* h1pm = (short*)(F + 0);          // [64][32][32][64] bf16
  short* h2pm = (short*)(F + 2097152);    // [64][16][16][128] bf16
  float* hf32 = F + 3145728;              // ds3 f32 identity [64][64][128]
  short* hbf = (short*)(F + 5242880);     // final h bf16 (fc input)
  float* stats = F + 6291456;             // 4 layers x 512 + counter + pad (zeroed 2064)
  unsigned* cnt = (unsigned*)(stats + 2048);
  float* fcpart = F + 6293568;            // 32 x [64][256] f32, ends 6817856 < 8388608
  short* h0pm = (short*)(F + 8388608);    // [64][4096][32] bf16
  short* wfcbf = (short*)(F + 12582912);
  short* wTr1 = (short*)(F + 13631488);
  short* wTr2 = wTr1 + 589824;
  short* wTds1 = wTr2 + 589824;
  short* wTds2 = wTds1 + 32768;
  short* wTds3 = wTds2 + 131072;
  short* wsc = wTds3 + 262144;            // 8192 shorts
  short* wproj = wsc + 8192;              // 2048 shorts

  k_wall<<<1425, 256, 0, stream>>>(rc1w, rc2w, d1w, d2w, d3w, fcw, c1w, pw,
                                   wTr1, wTr2, wTds1, wTds2, wTds3, wfcbf, wsc, wproj,
                                   scat, stats);
  k_scatmfma<<<512, 256, 0, stream>>>(emb, xy, wsc, scat);
  k_projmfma<<<2048, 256, 0, stream>>>(scat, xin, wproj, pb, h0pm);
  k_ds2<32, 64, 64, 2, 1, 4, 4, 0><<<1024, 256, 0, stream>>>(h0pm, wTds1, d1b, h1pm, nullptr);
  k_ds2<64, 128, 32, 1, 1, 1, 2, 0><<<1024, 256, 0, stream>>>(h1pm, wTds2, d2b, h2pm, nullptr);
  k_ds2<128, 128, 16, 2, 2, 1, 1, 2><<<512, 256, 0, stream>>>(h2pm, wTds3, d3b, nullptr, hf32);
  k_res4<<<64, 512, 0, stream>>>(hf32, wTr1, wTr2, rbn1g, rbn1b, rbn2g, rbn2b,
                                 stats, cnt, hbf, out0);
  k_fcmfma<<<128, 256, 0, stream>>>(hbf, wfcbf, fcpart);
  k_fcred<<<64, 256, 0, stream>>>(fcpart, fcb, out1);
}